// Round 5
// baseline (392.144 us; speedup 1.0000x reference)
//
#include <hip/hip_runtime.h>
#include <math.h>
#include <stdint.h>

#define D_    768
#define B_    16
#define S_    1024
#define M_    16
#define SM_   1040           // S + M
#define SMP_  1088           // padded kv length (17*64) for PV K-loop
#define SCALE_ 0.036084392f  // 1/sqrt(768)

typedef __bf16 bf16;
typedef __attribute__((ext_vector_type(8))) __bf16 bf16x8;
typedef __attribute__((ext_vector_type(4))) __bf16 bf16x4;
typedef __attribute__((ext_vector_type(4))) float  f32x4;

// async global->LDS, 16B per lane; LDS dest = wave-uniform base + lane*16
#define GL16(gp, lp) __builtin_amdgcn_global_load_lds( \
    (const __attribute__((address_space(1))) void*)(gp), \
    (__attribute__((address_space(3))) void*)(lp), 16, 0, 0)

// ---------------------------------------------------------------------------
// NT GEMM, 128x128 tile, BK=64, bf16 MFMA 16x16x32, 4 waves (2x2), 4x4 frags.
// C[row, col] = sum_k A[row,k] * B[col,k]
// global_load_lds width=16 staging; LDS [128][64] bf16 with 16B chunks
// XOR-swizzled within each 128B row (chunk p holds global chunk p^(row&7)).
//
// GM (grid mode):
//  1: flat XCD-swizzled, scores shape (8 rowtiles x 9 coltiles x 16 z):
//     xcd=bid&7 owns batches 2*xcd, 2*xcd+1 -> per-XCD L2 keeps Q+K resident
//  2: flat XCD-swizzled, PV shape (8 x 6 x 16): same idea for P+Vt
//  3: row0=by*128, col0=bx*128, z=0 (col-tile-fast; B fully L2-resident)
//  4: flat XCD row-affinity for QKV (130 rowtiles x 18 coltiles): xcd=bid&7,
//     work w=xcd*293+(bid>>3) ordered rowtile-major -> each XCD fetches a
//     contiguous ~1/8 of A's row tiles exactly once (w>=2340: no-op block)
//
// OUTMODE 1: fp32 row-major + bias.
// OUTMODE 3: fused QKV epilogue. B = [wq;wk;wv] (2304 rows), wsel=col0/768.
//   Q->Cout[b,t<1024,:] bf16; K->C2 [16640,768] bf16; V->C3 transposed
//   Vt[b,e,t] (ldc 1088) bf16x4 (4-groups never straddle batch boundary).
// OUTMODE 4: scores->probs epilogue: write bf16(exp(acc*SCALE + mask[t,col]))
//   for col<1040, 0 for col in [1040,1088) (pad), skip col>=1088. `aux` = mask
//   (fp32 [1024][1040]); t0 is the within-batch q row (GM=1 guarantees <1024).
//   No max-subtraction: scores ~ N(0,1), exp well inside fp32/bf16 range.
// OUTMODE 5: PV epilogue: out = bf16(acc * aux[z*1024 + row]) (aux = rinv).
// ---------------------------------------------------------------------------
template<int OUTMODE, int GM>
__launch_bounds__(256)
__global__ void gemm_k(const bf16*  __restrict__ Am,
                       const bf16*  __restrict__ Bm,
                       const float* __restrict__ aux,
                       void* __restrict__ Cout,
                       void* __restrict__ C2,
                       void* __restrict__ C3,
                       int lda, int ldb, int ldc,
                       int K, int colsB,
                       long sA, long sB, long sC)
{
    __shared__ __attribute__((aligned(16))) bf16 As[128 * 64];
    __shared__ __attribute__((aligned(16))) bf16 Bs[128 * 64];

    const int t    = threadIdx.x;
    const int l    = t & 63;
    const int wv   = t >> 6;

    int row0, col0, z;
    if (GM == 1) {
        const int bid = blockIdx.x;           // 1152 blocks
        const int xcd = bid & 7, s = bid >> 3;
        z = xcd * 2 + s / 72;
        const int r = s % 72;
        row0 = (r & 7) * 128; col0 = (r >> 3) * 128;
    } else if (GM == 2) {
        const int bid = blockIdx.x;           // 768 blocks
        const int xcd = bid & 7, s = bid >> 3;
        z = xcd * 2 + s / 48;
        const int r = s % 48;
        row0 = (r & 7) * 128; col0 = (r >> 3) * 128;
    } else if (GM == 4) {
        const int bid = blockIdx.x;           // 2344 blocks (4 no-ops)
        const int xcd = bid & 7, s = bid >> 3;
        const int w = xcd * 293 + s;
        if (w >= 2340) return;
        row0 = (w / 18) * 128; col0 = (w % 18) * 128; z = 0;
    } else {
        row0 = blockIdx.y * 128; col0 = blockIdx.x * 128; z = 0;
    }

    const bf16* agb[4];
    const bf16* bgb[4];
    #pragma unroll
    for (int i = 0; i < 4; ++i) {
        const int r = (wv * 4 + i) * 8 + (l >> 3);   // tile row 0..127
        const int c = (l & 7) ^ (r & 7);             // swizzled source chunk
        agb[i] = Am + (size_t)z * sA + (size_t)(row0 + r) * lda + c * 8;
        int bcol = col0 + r;
        if (bcol > colsB - 1) bcol = colsB - 1;
        bgb[i] = Bm + (size_t)z * sB + (size_t)bcol * ldb + c * 8;
    }

    f32x4 acc[4][4];
    #pragma unroll
    for (int i = 0; i < 4; ++i)
        #pragma unroll
        for (int j = 0; j < 4; ++j)
            acc[i][j] = (f32x4){0.f, 0.f, 0.f, 0.f};

    const int wr0 = (wv & 1) * 64;
    const int wc0 = (wv >> 1) * 64;
    const int lq  = l >> 4;
    const int lm  = l & 15;

    for (int kt = 0; kt < K; kt += 64) {
        __syncthreads();   // previous tile's fragment reads done
        #pragma unroll
        for (int i = 0; i < 4; ++i)
            GL16(agb[i] + kt, &As[(wv * 4 + i) * 512]);
        #pragma unroll
        for (int i = 0; i < 4; ++i)
            GL16(bgb[i] + kt, &Bs[(wv * 4 + i) * 512]);
        __syncthreads();   // staging visible

        #pragma unroll
        for (int ks = 0; ks < 2; ++ks) {
            bf16x8 af[4], bfr[4];
            #pragma unroll
            for (int i = 0; i < 4; ++i) {
                const int rowA = wr0 + i * 16 + lm;
                const int p = (ks * 4 + lq) ^ (rowA & 7);
                af[i] = *(const bf16x8*)&As[rowA * 64 + p * 8];
            }
            #pragma unroll
            for (int j = 0; j < 4; ++j) {
                const int rowB = wc0 + j * 16 + lm;
                const int p = (ks * 4 + lq) ^ (rowB & 7);
                bfr[j] = *(const bf16x8*)&Bs[rowB * 64 + p * 8];
            }
            #pragma unroll
            for (int i = 0; i < 4; ++i)
                #pragma unroll
                for (int j = 0; j < 4; ++j)
                    acc[i][j] = __builtin_amdgcn_mfma_f32_16x16x32_bf16(
                        af[i], bfr[j], acc[i][j], 0, 0, 0);
        }
    }

    // epilogue: C/D layout col=lane&15, row=quad*4+reg (m89/m91 verified)
    const int wsel = (OUTMODE == 3) ? (col0 / 768) : 0;
    #pragma unroll
    for (int j = 0; j < 4; ++j) {
        const int gcol = col0 + wc0 + j * 16 + lm;
        #pragma unroll
        for (int i = 0; i < 4; ++i) {
            const int t0 = row0 + wr0 + i * 16 + lq * 4;  // 4-aligned
            if (OUTMODE == 3) {
                const int lcol = gcol - wsel * 768;
                const float bv = aux[gcol];
                const int b  = t0 / SM_;
                const int tt = t0 - b * SM_;
                if (wsel == 0) {             // Q -> [B,1024,768] bf16
                    if (tt < S_) {
                        #pragma unroll
                        for (int r = 0; r < 4; ++r)
                            ((bf16*)Cout)[((size_t)b * S_ + tt + r) * D_ + lcol]
                                = (bf16)(acc[i][j][r] + bv);
                    }
                } else if (wsel == 1) {      // K -> [16640,768] bf16
                    #pragma unroll
                    for (int r = 0; r < 4; ++r)
                        ((bf16*)C2)[(size_t)(t0 + r) * D_ + lcol]
                            = (bf16)(acc[i][j][r] + bv);
                } else {                     // V -> Vt[b, e, t] bf16x4
                    bf16x4 o;
                    #pragma unroll
                    for (int r = 0; r < 4; ++r) o[r] = (bf16)(acc[i][j][r] + bv);
                    *(bf16x4*)((bf16*)C3 +
                        ((size_t)b * D_ + lcol) * SMP_ + tt) = o;
                }
            } else if (OUTMODE == 4) {       // probs (unnormalized)
                if (gcol < SMP_) {
                    #pragma unroll
                    for (int r = 0; r < 4; ++r) {
                        float val = 0.f;
                        if (gcol < SM_)
                            val = __expf(acc[i][j][r] * SCALE_
                                  + aux[(size_t)(t0 + r) * SM_ + gcol]);
                        ((bf16*)Cout)[(size_t)z * sC
                            + (size_t)(t0 + r) * ldc + gcol] = (bf16)val;
                    }
                }
            } else if (OUTMODE == 5) {       // PV, normalize by rinv
                #pragma unroll
                for (int r = 0; r < 4; ++r) {
                    const float ri = aux[z * S_ + t0 + r];
                    ((bf16*)Cout)[(size_t)z * sC + (size_t)(t0 + r) * ldc + gcol]
                        = (bf16)(acc[i][j][r] * ri);
                }
            } else {                         // OUTMODE 1: fp32 + bias
                if (gcol < colsB) {
                    const float bv = aux ? aux[gcol] : 0.f;
                    #pragma unroll
                    for (int r = 0; r < 4; ++r)
                        ((float*)Cout)[(size_t)z * sC
                            + (size_t)(t0 + r) * ldc + gcol]
                            = acc[i][j][r] + bv;
                }
            }
        }
    }
}

// ---------------------------------------------------------------------------
// Weight cast: wq/wk/wv -> one concatenated [2304,768] bf16 buffer, wo -> wob
// ---------------------------------------------------------------------------
__global__ void castw4_k(const float* __restrict__ w0, const float* __restrict__ w1,
                         const float* __restrict__ w2, const float* __restrict__ w3,
                         bf16* __restrict__ wqkv, bf16* __restrict__ wob)
{
    const float* in;
    bf16* out;
    const size_t NW = (size_t)D_ * D_;
    switch (blockIdx.y) {
        case 0: in = w0; out = wqkv;          break;
        case 1: in = w1; out = wqkv + NW;     break;
        case 2: in = w2; out = wqkv + 2 * NW; break;
        default: in = w3; out = wob;          break;
    }
    const int i = blockIdx.x * blockDim.x + threadIdx.x;   // float4 chunks
    const float4 f = ((const float4*)in)[i];
    bf16x4 v;
    v[0] = (bf16)f.x; v[1] = (bf16)f.y; v[2] = (bf16)f.z; v[3] = (bf16)f.w;
    ((bf16x4*)out)[i] = v;
}

// ---------------------------------------------------------------------------
// cstream[b*1040 + t][e] = bf16( t<1024 ? x[b,t,e] : mem[t-1024,e] )
// Last block (6240) instead concatenates bq|bk|bv into bqkv [2304] fp32.
// ---------------------------------------------------------------------------
__global__ void castx_k(const float* __restrict__ x, const float* __restrict__ mem,
                        bf16* __restrict__ cs,
                        const float* __restrict__ bq, const float* __restrict__ bk,
                        const float* __restrict__ bv, float* __restrict__ bqkv)
{
    if (blockIdx.x == 6240) {
        const int tid = threadIdx.x;
        if (tid < 576) {
            const int g = tid * 4;
            const float* src = (g < 768) ? (bq + g)
                             : (g < 1536) ? (bk + g - 768) : (bv + g - 1536);
            *(float4*)(bqkv + g) = *(const float4*)src;
        }
        return;
    }
    const int i = blockIdx.x * blockDim.x + threadIdx.x;  // 0 .. 16640*96-1
    const int row = i / 96;
    const int c8  = (i - row * 96) * 8;
    const int b   = row / SM_;
    const int tt  = row - b * SM_;
    const float* src = (tt < S_) ? (x + ((size_t)b * S_ + tt) * D_ + c8)
                                 : (mem + (size_t)(tt - S_) * D_ + c8);
    const float4 f0 = *(const float4*)src;
    const float4 f1 = *(const float4*)(src + 4);
    bf16x8 v;
    v[0] = (bf16)f0.x; v[1] = (bf16)f0.y; v[2] = (bf16)f0.z; v[3] = (bf16)f0.w;
    v[4] = (bf16)f1.x; v[5] = (bf16)f1.y; v[6] = (bf16)f1.z; v[7] = (bf16)f1.w;
    *(bf16x8*)(cs + (size_t)row * D_ + c8) = v;
}

// ---------------------------------------------------------------------------
// rinv[row] = 1 / sum(P[row, 0:1088])  (pad cols are 0; sums the bf16 values
// PV will actually consume). 4 rows/block, 64 lanes/row, 17*64 = 1088 exact.
// ---------------------------------------------------------------------------
__launch_bounds__(256)
__global__ void rowsum_k(const bf16* __restrict__ P, float* __restrict__ rinv)
{
    const int row = blockIdx.x * 4 + (threadIdx.x >> 6);
    const int l   = threadIdx.x & 63;
    const bf16* prow = P + (size_t)row * SMP_;
    float s = 0.f;
    #pragma unroll
    for (int it = 0; it < 17; ++it) s += (float)prow[l + it * 64];
    #pragma unroll
    for (int o = 32; o; o >>= 1) s += __shfl_xor(s, o);
    if (l == 0) rinv[row] = 1.f / s;
}

// ---------------------------------------------------------------------------
extern "C" void kernel_launch(void* const* d_in, const int* in_sizes, int n_in,
                              void* d_out, int out_size, void* d_ws, size_t ws_size,
                              hipStream_t stream) {
    const float* x    = (const float*)d_in[0];
    const float* mask = (const float*)d_in[1];
    const float* mem  = (const float*)d_in[2];
    const float* wq   = (const float*)d_in[3];
    const float* bq   = (const float*)d_in[4];
    const float* wk   = (const float*)d_in[5];
    const float* bk   = (const float*)d_in[6];
    const float* wv   = (const float*)d_in[7];
    const float* bv   = (const float*)d_in[8];
    const float* wo   = (const float*)d_in[9];
    const float* bo   = (const float*)d_in[10];

    bf16* w = (bf16*)d_ws;
    const size_t NW  = (size_t)D_ * D_;          //   589824
    const size_t NCS = (size_t)B_ * SM_ * D_;    // 12779520 (cstream / head_out)
    const size_t NQ  = (size_t)B_ * S_ * D_;     // 12582912
    const size_t NKV = (size_t)B_ * SM_ * D_;    // 12779520
    const size_t NVT = (size_t)B_ * D_ * SMP_;   // 13369344
    bf16* wqkv = w;                // [2304][768]
    bf16* wob  = wqkv + 3 * NW;
    bf16* cs   = wob + NW;         // concat(x, mem) bf16; reused as head_out
    bf16* qb   = cs  + NCS;
    bf16* kb   = qb  + NQ;
    bf16* vtb  = kb  + NKV;
    bf16* Pb   = vtb + NVT;        // [B,1024,1088] unnormalized probs
    float* bqkv = (float*)(Pb + (size_t)B_ * S_ * SMP_);  // [2304] fp32
    float* rinv = bqkv + 2304;                            // [16384] fp32

    castw4_k<<<dim3(576, 4), 256, 0, stream>>>(wq, wk, wv, wo, wqkv, wob);
    castx_k<<<6241, 256, 0, stream>>>(x, mem, cs, bq, bk, bv, bqkv);

    // fused QKV: cs @ [wq;wk;wv]^T + bqkv -> qb / kb / vtb(transposed)
    // GM=4: XCD row-affinity (each XCD owns ~16 contiguous A row tiles)
    gemm_k<3, 4><<<2344, 256, 0, stream>>>(
        cs, wqkv, bqkv, qb, kb, vtb, D_, D_, 0, D_, 3 * D_, 0, 0, 0);

    // P_unnorm = exp(q @ k^T * SCALE + mask), pad cols zeroed (XCD-swizzled)
    gemm_k<4, 1><<<1152, 256, 0, stream>>>(
        qb, kb, mask, Pb, nullptr, nullptr, D_, D_, SMP_, D_, SM_,
        (long)S_ * D_, (long)SM_ * D_, (long)S_ * SMP_);
    rowsum_k<<<(B_ * S_) / 4, 256, 0, stream>>>(Pb, rinv);

    // head_out = (P_unnorm @ V) * rinv  (XCD-swizzled) -> cs reused
    gemm_k<5, 2><<<768, 256, 0, stream>>>(
        Pb, vtb, rinv, cs, nullptr, nullptr, SMP_, SMP_, D_, SMP_, D_,
        (long)S_ * SMP_, (long)D_ * SMP_, (long)S_ * D_);

    // out = head_out @ wo^T + bo (fp32, col-tile-fast for A-tile L2 reuse)
    gemm_k<1, 3><<<dim3(6, 128), 256, 0, stream>>>(
        cs, wob, bo, d_out, nullptr, nullptr, D_, D_, D_, D_, D_, 0, 0, 0);
}

// Round 6
// 335.830 us; speedup vs baseline: 1.1677x; 1.1677x over previous
//
#include <hip/hip_runtime.h>
#include <math.h>
#include <stdint.h>

#define D_    768
#define B_    16
#define S_    1024
#define M_    16
#define SM_   1040           // S + M
#define SMP_  1088           // padded kv length (17*64) for PV K-loop
#define SCALE_ 0.036084392f  // 1/sqrt(768)

typedef __bf16 bf16;
typedef __attribute__((ext_vector_type(8))) __bf16 bf16x8;
typedef __attribute__((ext_vector_type(4))) __bf16 bf16x4;
typedef __attribute__((ext_vector_type(4))) float  f32x4;

// async global->LDS, 16B per lane; LDS dest = wave-uniform base + lane*16
#define GL16(gp, lp) __builtin_amdgcn_global_load_lds( \
    (const __attribute__((address_space(1))) void*)(gp), \
    (__attribute__((address_space(3))) void*)(lp), 16, 0, 0)

// ---------------------------------------------------------------------------
// NT GEMM, 128x128 tile, BK=64, bf16 MFMA 16x16x32, 4 waves (2x2), 4x4 frags.
// C[row, col] = sum_k A[row,k] * B[col,k]
// global_load_lds width=16 staging; LDS [128][64] bf16 with 16B chunks
// XOR-swizzled within each 128B row (chunk p holds global chunk p^(row&7)).
// __launch_bounds__(256,3): request 3 blocks/CU (144 unified regs < 170 cap).
//
// GM: 1 = flat XCD-swizzled scores (8 row x 9 col x 16 z; xcd owns 2 batches)
//     2 = flat XCD-swizzled PV (8 x 6 x 16)
//     3 = row0=by*128, col0=bx*128, z=0 (col-tile-fast)
//
// OUTMODE 1: fp32 row-major + bias (aux).
// OUTMODE 3: fused QKV. B=[wq*SCALE; wk; wv] (2304 rows), wsel=col0/768,
//   bias=aux (bqkv, bq pre-scaled). Q->Cout[b,t<1024,:] bf16;
//   K->C2 [16640,768] bf16; V->C3 Vt[b,e,t] (ldc 1088) bf16x4.
// OUTMODE 4: probs epilogue. P = bf16(exp(acc) * emask[t,col]) for col<1040
//   (emask = bf16(exp(mask)) via C3; SCALE pre-folded into wq), 0 for pad
//   cols [1040,1088), skip col>=1088. Per-row partial sums of the stored bf16
//   values wave-reduced and atomicAdd'ed into rsum (= C2, zero-initialized).
// OUTMODE 5: PV epilogue: out = bf16(acc / rsum[z*1024+row]) (rsum = aux).
// ---------------------------------------------------------------------------
template<int OUTMODE, int GM>
__launch_bounds__(256, 3)
__global__ void gemm_k(const bf16*  __restrict__ Am,
                       const bf16*  __restrict__ Bm,
                       const float* __restrict__ aux,
                       void* __restrict__ Cout,
                       void* __restrict__ C2,
                       void* __restrict__ C3,
                       int lda, int ldb, int ldc,
                       int K, int colsB,
                       long sA, long sB, long sC)
{
    __shared__ __attribute__((aligned(16))) bf16 As[128 * 64];
    __shared__ __attribute__((aligned(16))) bf16 Bs[128 * 64];

    const int t    = threadIdx.x;
    const int l    = t & 63;
    const int wv   = t >> 6;

    int row0, col0, z;
    if (GM == 1) {
        const int bid = blockIdx.x;           // 1152 blocks
        const int xcd = bid & 7, s = bid >> 3;
        z = xcd * 2 + s / 72;
        const int r = s % 72;
        row0 = (r & 7) * 128; col0 = (r >> 3) * 128;
    } else if (GM == 2) {
        const int bid = blockIdx.x;           // 768 blocks
        const int xcd = bid & 7, s = bid >> 3;
        z = xcd * 2 + s / 48;
        const int r = s % 48;
        row0 = (r & 7) * 128; col0 = (r >> 3) * 128;
    } else {
        row0 = blockIdx.y * 128; col0 = blockIdx.x * 128; z = 0;
    }

    const bf16* agb[4];
    const bf16* bgb[4];
    #pragma unroll
    for (int i = 0; i < 4; ++i) {
        const int r = (wv * 4 + i) * 8 + (l >> 3);   // tile row 0..127
        const int c = (l & 7) ^ (r & 7);             // swizzled source chunk
        agb[i] = Am + (size_t)z * sA + (size_t)(row0 + r) * lda + c * 8;
        int bcol = col0 + r;
        if (bcol > colsB - 1) bcol = colsB - 1;
        bgb[i] = Bm + (size_t)z * sB + (size_t)bcol * ldb + c * 8;
    }

    f32x4 acc[4][4];
    #pragma unroll
    for (int i = 0; i < 4; ++i)
        #pragma unroll
        for (int j = 0; j < 4; ++j)
            acc[i][j] = (f32x4){0.f, 0.f, 0.f, 0.f};

    const int wr0 = (wv & 1) * 64;
    const int wc0 = (wv >> 1) * 64;
    const int lq  = l >> 4;
    const int lm  = l & 15;

    for (int kt = 0; kt < K; kt += 64) {
        __syncthreads();   // previous tile's fragment reads done
        #pragma unroll
        for (int i = 0; i < 4; ++i)
            GL16(agb[i] + kt, &As[(wv * 4 + i) * 512]);
        #pragma unroll
        for (int i = 0; i < 4; ++i)
            GL16(bgb[i] + kt, &Bs[(wv * 4 + i) * 512]);
        __syncthreads();   // staging visible

        #pragma unroll
        for (int ks = 0; ks < 2; ++ks) {
            bf16x8 af[4], bfr[4];
            #pragma unroll
            for (int i = 0; i < 4; ++i) {
                const int rowA = wr0 + i * 16 + lm;
                const int p = (ks * 4 + lq) ^ (rowA & 7);
                af[i] = *(const bf16x8*)&As[rowA * 64 + p * 8];
            }
            #pragma unroll
            for (int j = 0; j < 4; ++j) {
                const int rowB = wc0 + j * 16 + lm;
                const int p = (ks * 4 + lq) ^ (rowB & 7);
                bfr[j] = *(const bf16x8*)&Bs[rowB * 64 + p * 8];
            }
            #pragma unroll
            for (int i = 0; i < 4; ++i)
                #pragma unroll
                for (int j = 0; j < 4; ++j)
                    acc[i][j] = __builtin_amdgcn_mfma_f32_16x16x32_bf16(
                        af[i], bfr[j], acc[i][j], 0, 0, 0);
        }
    }

    // epilogue: C/D layout col=lane&15, row=quad*4+reg (m89/m91 verified)
    if (OUTMODE == 4) {
        // probs + fused row-sum atomics
        const bf16* em = (const bf16*)C3;
        float* rsum = (float*)C2;
        #pragma unroll
        for (int i = 0; i < 4; ++i) {
            const int t0 = row0 + wr0 + i * 16 + lq * 4;
            #pragma unroll
            for (int r = 0; r < 4; ++r) {
                float part = 0.f;
                #pragma unroll
                for (int j = 0; j < 4; ++j) {
                    const int gcol = col0 + wc0 + j * 16 + lm;
                    float val = 0.f;
                    if (gcol < SM_)
                        val = __expf(acc[i][j][r])
                            * (float)em[(size_t)(t0 + r) * SM_ + gcol];
                    const bf16 vb = (bf16)val;
                    part += (float)vb;
                    if (gcol < SMP_)
                        ((bf16*)Cout)[(size_t)z * sC
                            + (size_t)(t0 + r) * ldc + gcol] = vb;
                }
                // reduce over the 16 lm lanes (lane bits 0..3)
                #pragma unroll
                for (int o = 8; o; o >>= 1) part += __shfl_xor(part, o);
                if (lm == 0)
                    atomicAdd(&rsum[z * S_ + t0 + r], part);
            }
        }
        return;
    }

    float rin[4][4];
    if (OUTMODE == 5) {
        #pragma unroll
        for (int i = 0; i < 4; ++i) {
            const int t0 = row0 + wr0 + i * 16 + lq * 4;
            #pragma unroll
            for (int r = 0; r < 4; ++r)
                rin[i][r] = 1.f / aux[z * S_ + t0 + r];
        }
    }

    const int wsel = (OUTMODE == 3) ? (col0 / 768) : 0;
    #pragma unroll
    for (int j = 0; j < 4; ++j) {
        const int gcol = col0 + wc0 + j * 16 + lm;
        #pragma unroll
        for (int i = 0; i < 4; ++i) {
            const int t0 = row0 + wr0 + i * 16 + lq * 4;  // 4-aligned
            if (OUTMODE == 3) {
                const int lcol = gcol - wsel * 768;
                const float bv = aux[gcol];
                const int b  = t0 / SM_;
                const int tt = t0 - b * SM_;
                if (wsel == 0) {             // Q -> [B,1024,768] bf16
                    if (tt < S_) {
                        #pragma unroll
                        for (int r = 0; r < 4; ++r)
                            ((bf16*)Cout)[((size_t)b * S_ + tt + r) * D_ + lcol]
                                = (bf16)(acc[i][j][r] + bv);
                    }
                } else if (wsel == 1) {      // K -> [16640,768] bf16
                    #pragma unroll
                    for (int r = 0; r < 4; ++r)
                        ((bf16*)C2)[(size_t)(t0 + r) * D_ + lcol]
                            = (bf16)(acc[i][j][r] + bv);
                } else {                     // V -> Vt[b, e, t] bf16x4
                    bf16x4 o;
                    #pragma unroll
                    for (int r = 0; r < 4; ++r) o[r] = (bf16)(acc[i][j][r] + bv);
                    *(bf16x4*)((bf16*)C3 +
                        ((size_t)b * D_ + lcol) * SMP_ + tt) = o;
                }
            } else if (OUTMODE == 5) {       // PV, normalize by row sum
                #pragma unroll
                for (int r = 0; r < 4; ++r)
                    ((bf16*)Cout)[(size_t)z * sC + (size_t)(t0 + r) * ldc + gcol]
                        = (bf16)(acc[i][j][r] * rin[i][r]);
            } else {                         // OUTMODE 1: fp32 + bias
                if (gcol < colsB) {
                    const float bv = aux ? aux[gcol] : 0.f;
                    #pragma unroll
                    for (int r = 0; r < 4; ++r)
                        ((float*)Cout)[(size_t)z * sC
                            + (size_t)(t0 + r) * ldc + gcol]
                            = acc[i][j][r] + bv;
                }
            }
        }
    }
}

// ---------------------------------------------------------------------------
// Weight cast: [wq*SCALE; wk; wv] -> wqkv [2304,768] bf16, wo -> wob
// ---------------------------------------------------------------------------
__global__ void castw4_k(const float* __restrict__ w0, const float* __restrict__ w1,
                         const float* __restrict__ w2, const float* __restrict__ w3,
                         bf16* __restrict__ wqkv, bf16* __restrict__ wob)
{
    const float* in;
    bf16* out;
    float sc = 1.f;
    const size_t NW = (size_t)D_ * D_;
    switch (blockIdx.y) {
        case 0: in = w0; out = wqkv;          sc = SCALE_; break;
        case 1: in = w1; out = wqkv + NW;     break;
        case 2: in = w2; out = wqkv + 2 * NW; break;
        default: in = w3; out = wob;          break;
    }
    const int i = blockIdx.x * blockDim.x + threadIdx.x;   // float4 chunks
    const float4 f = ((const float4*)in)[i];
    bf16x4 v;
    v[0] = (bf16)(f.x * sc); v[1] = (bf16)(f.y * sc);
    v[2] = (bf16)(f.z * sc); v[3] = (bf16)(f.w * sc);
    ((bf16x4*)out)[i] = v;
}

// ---------------------------------------------------------------------------
// emask[t, col] = bf16(exp(mask[t, col]))   (1024 x 1040)
// ---------------------------------------------------------------------------
__global__ void emask_k(const float* __restrict__ mask, bf16* __restrict__ em)
{
    const int i = blockIdx.x * blockDim.x + threadIdx.x;  // float4 chunks
    const float4 f = ((const float4*)mask)[i];
    bf16x4 v;
    v[0] = (bf16)__expf(f.x); v[1] = (bf16)__expf(f.y);
    v[2] = (bf16)__expf(f.z); v[3] = (bf16)__expf(f.w);
    ((bf16x4*)em)[i] = v;
}

// ---------------------------------------------------------------------------
// cstream[b*1040 + t][e] = bf16( t<1024 ? x[b,t,e] : mem[t-1024,e] )
// Block 6240: concat bq*SCALE|bk|bv into bqkv [2304] and zero rsum [16384].
// ---------------------------------------------------------------------------
__global__ void castx_k(const float* __restrict__ x, const float* __restrict__ mem,
                        bf16* __restrict__ cs,
                        const float* __restrict__ bq, const float* __restrict__ bk,
                        const float* __restrict__ bv, float* __restrict__ bqkv,
                        float* __restrict__ rsum)
{
    if (blockIdx.x == 6240) {
        const int tid = threadIdx.x;
        if (tid < 576) {
            const int g = tid * 4;
            float4 f;
            if (g < 768) {
                f = *(const float4*)(bq + g);
                f.x *= SCALE_; f.y *= SCALE_; f.z *= SCALE_; f.w *= SCALE_;
            } else if (g < 1536) {
                f = *(const float4*)(bk + g - 768);
            } else {
                f = *(const float4*)(bv + g - 1536);
            }
            *(float4*)(bqkv + g) = f;
        }
        const float4 zz = make_float4(0.f, 0.f, 0.f, 0.f);
        #pragma unroll
        for (int k = 0; k < 16; ++k)
            *(float4*)(rsum + tid * 64 + k * 4) = zz;
        return;
    }
    const int i = blockIdx.x * blockDim.x + threadIdx.x;  // 0 .. 16640*96-1
    const int row = i / 96;
    const int c8  = (i - row * 96) * 8;
    const int b   = row / SM_;
    const int tt  = row - b * SM_;
    const float* src = (tt < S_) ? (x + ((size_t)b * S_ + tt) * D_ + c8)
                                 : (mem + (size_t)(tt - S_) * D_ + c8);
    const float4 f0 = *(const float4*)src;
    const float4 f1 = *(const float4*)(src + 4);
    bf16x8 v;
    v[0] = (bf16)f0.x; v[1] = (bf16)f0.y; v[2] = (bf16)f0.z; v[3] = (bf16)f0.w;
    v[4] = (bf16)f1.x; v[5] = (bf16)f1.y; v[6] = (bf16)f1.z; v[7] = (bf16)f1.w;
    *(bf16x8*)(cs + (size_t)row * D_ + c8) = v;
}

// ---------------------------------------------------------------------------
extern "C" void kernel_launch(void* const* d_in, const int* in_sizes, int n_in,
                              void* d_out, int out_size, void* d_ws, size_t ws_size,
                              hipStream_t stream) {
    const float* x    = (const float*)d_in[0];
    const float* mask = (const float*)d_in[1];
    const float* mem  = (const float*)d_in[2];
    const float* wq   = (const float*)d_in[3];
    const float* bq   = (const float*)d_in[4];
    const float* wk   = (const float*)d_in[5];
    const float* bk   = (const float*)d_in[6];
    const float* wv   = (const float*)d_in[7];
    const float* bv   = (const float*)d_in[8];
    const float* wo   = (const float*)d_in[9];
    const float* bo   = (const float*)d_in[10];

    bf16* w = (bf16*)d_ws;
    const size_t NW  = (size_t)D_ * D_;          //   589824
    const size_t NCS = (size_t)B_ * SM_ * D_;    // 12779520 (cstream / head_out)
    const size_t NQ  = (size_t)B_ * S_ * D_;     // 12582912
    const size_t NKV = (size_t)B_ * SM_ * D_;    // 12779520
    const size_t NVT = (size_t)B_ * D_ * SMP_;   // 13369344
    const size_t NEM = (size_t)S_ * SM_;         //  1064960
    bf16* wqkv = w;                // [2304][768] (wq pre-scaled)
    bf16* wob  = wqkv + 3 * NW;
    bf16* emb  = wob + NW;         // emask bf16 [1024][1040]
    bf16* cs   = emb + NEM;        // concat(x, mem) bf16; reused as head_out
    bf16* qb   = cs  + NCS;
    bf16* kb   = qb  + NQ;
    bf16* vtb  = kb  + NKV;
    bf16* Pb   = vtb + NVT;        // [B,1024,1088] unnormalized probs
    float* bqkv = (float*)(Pb + (size_t)B_ * S_ * SMP_);  // [2304] fp32
    float* rsum = bqkv + 2304;                            // [16384] fp32

    castw4_k<<<dim3(576, 4), 256, 0, stream>>>(wq, wk, wv, wo, wqkv, wob);
    emask_k<<<1040, 256, 0, stream>>>(mask, emb);
    castx_k<<<6241, 256, 0, stream>>>(x, mem, cs, bq, bk, bv, bqkv, rsum);

    // fused QKV: cs @ [wq*SC; wk; wv]^T + bqkv -> qb / kb / vtb(transposed)
    gemm_k<3, 3><<<dim3(18, 130), 256, 0, stream>>>(
        cs, wqkv, bqkv, qb, kb, vtb, D_, D_, 0, D_, 3 * D_, 0, 0, 0);

    // P_unnorm = exp(q @ k^T) * emask; per-row sums atomically -> rsum
    gemm_k<4, 1><<<1152, 256, 0, stream>>>(
        qb, kb, nullptr, Pb, rsum, emb, D_, D_, SMP_, D_, SM_,
        (long)S_ * D_, (long)SM_ * D_, (long)S_ * SMP_);

    // head_out = (P_unnorm @ V) / rsum  (XCD-swizzled) -> cs reused
    gemm_k<5, 2><<<768, 256, 0, stream>>>(
        Pb, vtb, rsum, cs, nullptr, nullptr, SMP_, SMP_, D_, SMP_, D_,
        (long)S_ * SMP_, (long)D_ * SMP_, (long)S_ * D_);

    // out = head_out @ wo^T + bo (fp32, col-tile-fast for A-tile L2 reuse)
    gemm_k<1, 3><<<dim3(6, 128), 256, 0, stream>>>(
        cs, wob, bo, d_out, nullptr, nullptr, D_, D_, D_, D_, D_, 0, 0, 0);
}